// Round 2
// baseline (369.380 us; speedup 1.0000x reference)
//
#include <hip/hip_runtime.h>
#include <stdint.h>

#define BB     64
#define CC     12
#define LL     2048
#define KERNSZ 9
#define KK     8     // kernels per group
#define GG     32    // groups per branch (_G)
#define NPER   6
#define NDIL   8
#define PAD    128   // halo covers D<=32 exactly; D=64/128 clamp boundary iters
#define MAIN   2048
#define BUFSZ  (PAD + MAIN + PAD)   // 2304 floats = 9216 B per wave
#define WPB    4                    // 36864 B/block -> 4 blocks/CU guaranteed

typedef float f2 __attribute__((ext_vector_type(2)));
typedef float f4 __attribute__((ext_vector_type(4)));

// acc.{lo,hi} += t.lo * w.{lo,hi}   (tap broadcast via op_sel_hi[0]=0;
// weights are a wave-uniform SGPR pair -> no VGPR replication, no spill)
__device__ __forceinline__ void pk_fma_bcast(f2& acc, const f2& t, uint64_t wpair) {
    asm("v_pk_fma_f32 %0, %1, %2, %0 op_sel:[0,0,0] op_sel_hi:[0,1,1]"
        : "+v"(acc) : "v"(t), "s"(wpair));
}
__device__ __forceinline__ f2 pk_mul_bcast(const f2& t, uint64_t wpair) {
    f2 d;
    asm("v_pk_mul_f32 %0, %1, %2 op_sel:[0,0] op_sel_hi:[0,1]"
        : "=v"(d) : "v"(t), "s"(wpair));
    return d;
}
// guaranteed 3-input max/min (clang sometimes fails to fuse fmaxf chains)
__device__ __forceinline__ float max3f(float a, float b, float c) {
    float d; asm("v_max3_f32 %0, %1, %2, %3" : "=v"(d) : "v"(a), "v"(b), "v"(c)); return d;
}
__device__ __forceinline__ float min3f(float a, float b, float c) {
    float d; asm("v_min3_f32 %0, %1, %2, %3" : "=v"(d) : "v"(a), "v"(b), "v"(c)); return d;
}

// One q-iteration (64 positions). CL = clamp tap offsets into the zeroed pads
// (boundary iterations of D=64/128 only; clamped tap reads 0 == old zero-pad).
template <int D, bool CL>
__device__ __forceinline__ void pos_body(
    const float* __restrict__ sel, int q, int lane, bool kill,
    const uint64_t (&wp)[4][KERNSZ], float (&accM)[KK], uint32_t (&cnt)[KK])
{
    const int pos = q * 64 + lane;

    f2 t[KERNSZ];                          // only .x meaningful; f2 forces
    #pragma unroll                         // even-aligned VGPR pair for asm
    for (int j = 0; j < KERNSZ; ++j) {
        int off = pos + (j - 4) * D;
        if constexpr (CL) {
            off = (off < -PAD) ? -PAD : off;
            off = (off > MAIN + PAD - 1) ? (MAIN + PAD - 1) : off;
        }
        t[j].x = sel[off];
    }

    f2 v2[4];                              // (v0,v1)(v2,v3)(v4,v5)(v6,v7)
    #pragma unroll
    for (int c = 0; c < 4; ++c)
        v2[c] = pk_mul_bcast(t[0], wp[c][0]);
    #pragma unroll
    for (int j = 1; j < KERNSZ; ++j)
        #pragma unroll
        for (int c = 0; c < 4; ++c)
            pk_fma_bcast(v2[c], t[j], wp[c][j]);

    float v[KK] = { v2[0].x, v2[0].y, v2[1].x, v2[1].y,
                    v2[2].x, v2[2].y, v2[3].x, v2[3].y };

    float ma = max3f(v[0], v[1], v[2]);
    float mb = max3f(v[3], v[4], v[5]);
    float mc = max3f(v[6], v[7], ma);
    float mv = fmaxf(mb, mc);
    float na = min3f(v[0], v[1], v[2]);
    float nb = min3f(v[3], v[4], v[5]);
    float nc = min3f(v[6], v[7], na);
    float nv = fminf(nb, nc);

    // only invalid output position: pos==2047 on diff branch.
    // NaN never compares equal -> contributes nothing below.
    if (kill && lane == 63) {
        const float NANF = __uint_as_float(0x7fc00000u);
        mv = NANF; nv = NANF;
    }

    #pragma unroll
    for (int k = 0; k < KK; ++k) {
        accM[k] += (v[k] == mv) ? v[k] : 0.0f;   // exact: mv bit-equals winner
        // argmin count via ballot: v_cmp (VALU) + bcnt/add (idle SALU pipe);
        // cnt[] is wave-uniform -> lives in SGPRs, no tail butterfly needed
        cnt[k] += (uint32_t)__popcll(__ballot(v[k] == nv));
    }
}

// Phase 2, specialized on compile-time dilation D (tap offsets are immediates).
template <int D>
__device__ __forceinline__ void run_phase2(
    const float* __restrict__ sel, int lane, int dif,
    const uint64_t (&wp)[4][KERNSZ], float (&accM)[KK], uint32_t (&cnt)[KK])
{
    constexpr int HALO = 4 * D;
    constexpr bool NEEDCL = (HALO > PAD);
    constexpr int QLO = NEEDCL ? (HALO - PAD + 63) / 64 : 0;        // first fast q
    constexpr int QHI = NEEDCL ? (2112 - HALO) / 64 + 1 : 32;       // first right-clamped q
    constexpr int QMID_END = (QHI < 31) ? QHI : 31;

    #pragma unroll
    for (int q = 0; q < QLO; ++q)
        pos_body<D, true>(sel, q, lane, false, wp, accM, cnt);
    #pragma unroll 2
    for (int q = QLO; q < QMID_END; ++q)
        pos_body<D, false>(sel, q, lane, false, wp, accM, cnt);
    #pragma unroll
    for (int q = QMID_END; q < 31; ++q)
        pos_body<D, true>(sel, q, lane, false, wp, accM, cnt);
    // last iteration carries the diff-branch kill of pos 2047
    pos_body<D, NEEDCL>(sel, 31, lane, dif != 0, wp, accM, cnt);
}

__global__ __launch_bounds__(256, 4) void hydra_kernel(
    const float* __restrict__ X,    // [B, C, L]
    const float* __restrict__ W,    // [NDIL, 2, KK*GG, 1, KERNSZ]
    const int*   __restrict__ I,    // [NDIL, 2, GG, NPER]
    float*       __restrict__ out)  // [B, 8192]
{
    __shared__ float lds[WPB][BUFSZ];

    const int tid  = threadIdx.x;
    const int wave = tid >> 6;
    const int lane = tid & 63;
    const int wid  = blockIdx.x * WPB + wave;   // 0..32767
    // task decode: wid = b*512 + di*64 + dif*32 + g
    const int b   = wid >> 9;
    const int r   = wid & 511;
    const int di  = r >> 6;
    const int r2  = r & 63;
    const int dif = r2 >> 5;
    const int g   = r2 & 31;

    float* buf = lds[wave];
    float* sel = buf + PAD;

    // ---- zero halo pads (64 lanes x float2 = 128 floats per side) ----
    {
        f2 z = {0.0f, 0.0f};
        ((f2*)buf)[lane]              = z;   // left pad
        ((f2*)(buf + PAD + MAIN))[lane] = z; // right pad
    }

    // ---- phase 1: channel-subset sum S into sel[0..2047] (dwordx4 loads) ----
    const int* Ig = I + ((size_t)((di * 2 + dif) * GG + g)) * NPER;
    const float* xb = X + (size_t)b * CC * LL;
    const f4* c0 = (const f4*)(xb + Ig[0] * LL);
    const f4* c1 = (const f4*)(xb + Ig[1] * LL);
    const f4* c2 = (const f4*)(xb + Ig[2] * LL);
    const f4* c3 = (const f4*)(xb + Ig[3] * LL);
    const f4* c4 = (const f4*)(xb + Ig[4] * LL);
    const f4* c5 = (const f4*)(xb + Ig[5] * LL);
    f4* sel4 = (f4*)sel;

    #pragma unroll 2
    for (int q = 0; q < 8; ++q) {
        int idx = q * 64 + lane;                  // float4 index, 512 quads total
        f4 s = (c0[idx] + c1[idx]) + (c2[idx] + c3[idx]) + (c4[idx] + c5[idx]);
        sel4[idx] = s;
    }

    if (dif) {
        // in-place wave-synchronous forward diff, vectorized. Per-wave LDS ops
        // are in program order: all lanes' reads of iteration q issue before
        // its writes; the extra scalar read at idx*4+4 targets data written
        // only later (lane l+1 this iter, or region of iter q+1).
        #pragma unroll 2
        for (int q = 0; q < 8; ++q) {
            int idx = q * 64 + lane;              // quad index
            f4 a  = sel4[idx];
            float an = sel[idx * 4 + 4];          // sel[2048] is the zeroed pad
            f4 v;
            v.x = a.y - a.x;
            v.y = a.z - a.y;
            v.z = a.w - a.z;
            v.w = (idx == 511) ? 0.0f : (an - a.w);   // pos 2047 -> 0
            sel4[idx] = v;
        }
    }

    // ---- weights: wave-uniform scalar loads, packed into SGPR pairs ----
    const float* Wg = W + (size_t)((di * 2 + dif) * (KK * GG) + g * KK) * KERNSZ;
    uint64_t wp[4][KERNSZ];   // wp[c][j] = (w[2c][j], w[2c+1][j])
    #pragma unroll
    for (int c = 0; c < 4; ++c)
        #pragma unroll
        for (int j = 0; j < KERNSZ; ++j) {
            uint32_t lo = __float_as_uint(Wg[(2 * c)     * KERNSZ + j]);
            uint32_t hi = __float_as_uint(Wg[(2 * c + 1) * KERNSZ + j]);
            wp[c][j] = (uint64_t)lo | ((uint64_t)hi << 32);
        }

    float    accM[KK];
    uint32_t cnt[KK];
    #pragma unroll
    for (int k = 0; k < KK; ++k) { accM[k] = 0.0f; cnt[k] = 0u; }

    switch (di) {   // block-uniform branch
        case 0: run_phase2<1>  (sel, lane, dif, wp, accM, cnt); break;
        case 1: run_phase2<2>  (sel, lane, dif, wp, accM, cnt); break;
        case 2: run_phase2<4>  (sel, lane, dif, wp, accM, cnt); break;
        case 3: run_phase2<8>  (sel, lane, dif, wp, accM, cnt); break;
        case 4: run_phase2<16> (sel, lane, dif, wp, accM, cnt); break;
        case 5: run_phase2<32> (sel, lane, dif, wp, accM, cnt); break;
        case 6: run_phase2<64> (sel, lane, dif, wp, accM, cnt); break;
        default: run_phase2<128>(sel, lane, dif, wp, accM, cnt); break;
    }

    // ---- tail: butterfly-reduce accM only; cnt is already wave-uniform ----
    float* o = out + (size_t)b * 8192 + (size_t)((di * 2 + dif) * 2) * 256 + g * KK;
    #pragma unroll
    for (int k = 0; k < KK; ++k) {
        float a = accM[k];
        #pragma unroll
        for (int off = 32; off > 0; off >>= 1)
            a += __shfl_xor(a, off, 64);
        if (lane == 0) {
            o[k]       = a;               // count_max block (which=0)
            o[256 + k] = (float)cnt[k];   // count_min block (which=1)
        }
    }
}

extern "C" void kernel_launch(void* const* d_in, const int* in_sizes, int n_in,
                              void* d_out, int out_size, void* d_ws, size_t ws_size,
                              hipStream_t stream) {
    const float* X = (const float*)d_in[0];
    const float* W = (const float*)d_in[1];
    const int*   I = (const int*)d_in[2];
    float* out = (float*)d_out;

    const int total_waves = BB * NDIL * 2 * GG;       // 32768
    const int blocks = total_waves / WPB;             // 8192
    hydra_kernel<<<blocks, 256, 0, stream>>>(X, W, I, out);
}

// Round 3
// 252.056 us; speedup vs baseline: 1.4655x; 1.4655x over previous
//
#include <hip/hip_runtime.h>
#include <stdint.h>

#define BB     64
#define CC     12
#define LL     2048
#define KERNSZ 9
#define KK     8     // kernels per group
#define GG     32    // groups per branch (_G)
#define NPER   6
#define NDIL   8
#define PAD    256   // halo covers D<=64 exactly; D=128 uses clamped taps
#define MAIN   2048
#define BUFSZ  (PAD + MAIN + PAD)   // 2560 floats = 10 KB per wave
#define WPB    4                    // 4 waves -> 40 KB LDS

typedef float f2 __attribute__((ext_vector_type(2)));
typedef float f4 __attribute__((ext_vector_type(4)));

// acc.{lo,hi} += t.lo * w.{lo,hi}   (tap broadcast via op_sel_hi[0]=0;
// weights are a wave-uniform SGPR pair -> no VGPR replication, no spill)
__device__ __forceinline__ void pk_fma_bcast(f2& acc, const f2& t, uint64_t wpair) {
    asm("v_pk_fma_f32 %0, %1, %2, %0 op_sel:[0,0,0] op_sel_hi:[0,1,1]"
        : "+v"(acc) : "v"(t), "s"(wpair));
}
__device__ __forceinline__ f2 pk_mul_bcast(const f2& t, uint64_t wpair) {
    f2 d;
    asm("v_pk_mul_f32 %0, %1, %2 op_sel:[0,0] op_sel_hi:[0,1]"
        : "=v"(d) : "v"(t), "s"(wpair));
    return d;
}
// guaranteed 3-input max/min (insurance against unfused fmaxf chains)
__device__ __forceinline__ float max3f(float a, float b, float c) {
    float d; asm("v_max3_f32 %0, %1, %2, %3" : "=v"(d) : "v"(a), "v"(b), "v"(c)); return d;
}
__device__ __forceinline__ float min3f(float a, float b, float c) {
    float d; asm("v_min3_f32 %0, %1, %2, %3" : "=v"(d) : "v"(a), "v"(b), "v"(c)); return d;
}

// Phase 2, specialized on compile-time dilation D (tap offsets are immediates).
// Structure identical to the proven R1 kernel (single uniform loop, kill inside);
// only the accN->ballot change and max3/min3 helpers differ.
template <int D>
__device__ __forceinline__ void run_phase2(
    const float* __restrict__ sel, int lane, int dif,
    const uint64_t (&wp)[4][KERNSZ], float (&accM)[KK], uint32_t (&cnt)[KK])
{
    const float NANF = __uint_as_float(0x7fc00000u);

    #pragma unroll 2
    for (int q = 0; q < 32; ++q) {
        const int pos = q * 64 + lane;

        f2 t[KERNSZ];                          // only .x meaningful; f2 forces
                                               // even-aligned VGPR pair for asm
        if constexpr (D == 128) {
            // halo is only 256; clamp OOB taps into the zeroed pads -> tap=0,
            // identical contribution to what 512-wide zero padding gave.
            #pragma unroll
            for (int j = 0; j < KERNSZ; ++j) {
                int off = pos + (j - 4) * D;
                if (j < 4) off = (off < -PAD) ? -PAD : off;
                if (j > 4) off = (off > MAIN + PAD - 1) ? (MAIN + PAD - 1) : off;
                t[j].x = sel[off];
            }
        } else {
            const float* p = sel + pos - 4 * D;   // pads make all 9 taps valid
            #pragma unroll
            for (int j = 0; j < KERNSZ; ++j)
                t[j].x = p[j * D];
        }

        f2 v2[4];                              // (v0,v1)(v2,v3)(v4,v5)(v6,v7)
        #pragma unroll
        for (int c = 0; c < 4; ++c)
            v2[c] = pk_mul_bcast(t[0], wp[c][0]);
        #pragma unroll
        for (int j = 1; j < KERNSZ; ++j)
            #pragma unroll
            for (int c = 0; c < 4; ++c)
                pk_fma_bcast(v2[c], t[j], wp[c][j]);

        float v[KK] = { v2[0].x, v2[0].y, v2[1].x, v2[1].y,
                        v2[2].x, v2[2].y, v2[3].x, v2[3].y };

        float ma = max3f(v[0], v[1], v[2]);
        float mb = max3f(v[3], v[4], v[5]);
        float mc = max3f(v[6], v[7], ma);
        float mv = fmaxf(mb, mc);
        float na = min3f(v[0], v[1], v[2]);
        float nb = min3f(v[3], v[4], v[5]);
        float nc = min3f(v[6], v[7], na);
        float nv = fminf(nb, nc);

        // only invalid output position: pos==2047 on diff branch.
        // NaN never compares equal -> contributes nothing below.
        if (dif && q == 31) {
            if (lane == 63) { mv = NANF; nv = NANF; }
        }

        #pragma unroll
        for (int k = 0; k < KK; ++k) {
            accM[k] += (v[k] == mv) ? v[k] : 0.0f;   // exact: mv bit-equals winner
            // argmin count via ballot: v_cmp (VALU) + bcnt/add on the idle SALU
            // pipe; cnt[] is wave-uniform -> SGPRs, no tail butterfly needed
            cnt[k] += (uint32_t)__popcll(__ballot(v[k] == nv));
        }
    }
}

__global__ __launch_bounds__(256, 4) void hydra_kernel(
    const float* __restrict__ X,    // [B, C, L]
    const float* __restrict__ W,    // [NDIL, 2, KK*GG, 1, KERNSZ]
    const int*   __restrict__ I,    // [NDIL, 2, GG, NPER]
    float*       __restrict__ out)  // [B, 8192]
{
    __shared__ float lds[WPB][BUFSZ];

    const int tid  = threadIdx.x;
    const int wave = tid >> 6;
    const int lane = tid & 63;
    const int wid  = blockIdx.x * WPB + wave;   // 0..32767
    // task decode: wid = b*512 + di*64 + dif*32 + g
    const int b   = wid >> 9;
    const int r   = wid & 511;
    const int di  = r >> 6;
    const int r2  = r & 63;
    const int dif = r2 >> 5;
    const int g   = r2 & 31;

    float* buf = lds[wave];
    float* sel = buf + PAD;

    // ---- zero halo pads (vectorized: 64 lanes x float4 = 256 floats) ----
    {
        f4 z = {0.0f, 0.0f, 0.0f, 0.0f};
        ((f4*)buf)[lane]                = z;   // left pad
        ((f4*)(buf + PAD + MAIN))[lane] = z;   // right pad
    }

    // ---- phase 1: channel-subset sum S into sel[0..2047] (dwordx4 loads) ----
    const int* Ig = I + ((size_t)((di * 2 + dif) * GG + g)) * NPER;
    const float* xb = X + (size_t)b * CC * LL;
    const f4* c0 = (const f4*)(xb + Ig[0] * LL);
    const f4* c1 = (const f4*)(xb + Ig[1] * LL);
    const f4* c2 = (const f4*)(xb + Ig[2] * LL);
    const f4* c3 = (const f4*)(xb + Ig[3] * LL);
    const f4* c4 = (const f4*)(xb + Ig[4] * LL);
    const f4* c5 = (const f4*)(xb + Ig[5] * LL);
    f4* sel4 = (f4*)sel;

    #pragma unroll 2
    for (int q = 0; q < 8; ++q) {
        int idx = q * 64 + lane;                  // float4 index, 512 quads total
        f4 s = (c0[idx] + c1[idx]) + (c2[idx] + c3[idx]) + (c4[idx] + c5[idx]);
        sel4[idx] = s;
    }

    if (dif) {
        // in-place wave-synchronous forward diff, vectorized. Per-wave LDS ops
        // are in program order: all lanes' reads of iteration q issue before
        // its writes; the extra scalar read at idx*4+4 targets data written
        // only later (lane l+1 this iter, or region of iter q+1).
        #pragma unroll 2
        for (int q = 0; q < 8; ++q) {
            int idx = q * 64 + lane;              // quad index
            f4 a  = sel4[idx];
            float an = sel[idx * 4 + 4];          // sel[2048] is the zeroed pad
            f4 v;
            v.x = a.y - a.x;
            v.y = a.z - a.y;
            v.z = a.w - a.z;
            v.w = (idx == 511) ? 0.0f : (an - a.w);   // pos 2047 -> 0
            sel4[idx] = v;
        }
    }

    // ---- weights: wave-uniform scalar loads, packed into SGPR pairs ----
    const float* Wg = W + (size_t)((di * 2 + dif) * (KK * GG) + g * KK) * KERNSZ;
    uint64_t wp[4][KERNSZ];   // wp[c][j] = (w[2c][j], w[2c+1][j])
    #pragma unroll
    for (int c = 0; c < 4; ++c)
        #pragma unroll
        for (int j = 0; j < KERNSZ; ++j) {
            uint32_t lo = __float_as_uint(Wg[(2 * c)     * KERNSZ + j]);
            uint32_t hi = __float_as_uint(Wg[(2 * c + 1) * KERNSZ + j]);
            wp[c][j] = (uint64_t)lo | ((uint64_t)hi << 32);
        }

    float    accM[KK];
    uint32_t cnt[KK];
    #pragma unroll
    for (int k = 0; k < KK; ++k) { accM[k] = 0.0f; cnt[k] = 0u; }

    switch (di) {   // block-uniform branch
        case 0: run_phase2<1>  (sel, lane, dif, wp, accM, cnt); break;
        case 1: run_phase2<2>  (sel, lane, dif, wp, accM, cnt); break;
        case 2: run_phase2<4>  (sel, lane, dif, wp, accM, cnt); break;
        case 3: run_phase2<8>  (sel, lane, dif, wp, accM, cnt); break;
        case 4: run_phase2<16> (sel, lane, dif, wp, accM, cnt); break;
        case 5: run_phase2<32> (sel, lane, dif, wp, accM, cnt); break;
        case 6: run_phase2<64> (sel, lane, dif, wp, accM, cnt); break;
        default: run_phase2<128>(sel, lane, dif, wp, accM, cnt); break;
    }

    // ---- tail: butterfly-reduce accM only; cnt is already wave-uniform ----
    float* o = out + (size_t)b * 8192 + (size_t)((di * 2 + dif) * 2) * 256 + g * KK;
    #pragma unroll
    for (int k = 0; k < KK; ++k) {
        float a = accM[k];
        #pragma unroll
        for (int off = 32; off > 0; off >>= 1)
            a += __shfl_xor(a, off, 64);
        if (lane == 0) {
            o[k]       = a;               // count_max block (which=0)
            o[256 + k] = (float)cnt[k];   // count_min block (which=1)
        }
    }
}

extern "C" void kernel_launch(void* const* d_in, const int* in_sizes, int n_in,
                              void* d_out, int out_size, void* d_ws, size_t ws_size,
                              hipStream_t stream) {
    const float* X = (const float*)d_in[0];
    const float* W = (const float*)d_in[1];
    const int*   I = (const int*)d_in[2];
    float* out = (float*)d_out;

    const int total_waves = BB * NDIL * 2 * GG;       // 32768
    const int blocks = total_waves / WPB;             // 8192
    hydra_kernel<<<blocks, 256, 0, stream>>>(X, W, I, out);
}

// Round 4
// 243.489 us; speedup vs baseline: 1.5170x; 1.0352x over previous
//
#include <hip/hip_runtime.h>
#include <stdint.h>

#define BB     64
#define CC     12
#define LL     2048
#define KERNSZ 9
#define KK     8     // kernels per group
#define GG     32    // groups per branch (_G)
#define NPER   6
#define NDIL   8
#define PAD    256   // halo covers D<=64 exactly; D=128 uses clamped taps
#define MAIN   2048
#define BUFSZ  (PAD + MAIN + PAD)   // 2560 floats = 10240 B per block (1 wave)

typedef float f2 __attribute__((ext_vector_type(2)));
typedef float f4 __attribute__((ext_vector_type(4)));

// acc.{lo,hi} += t.lo * w.{lo,hi}   (tap broadcast via op_sel_hi[0]=0;
// weights are a wave-uniform SGPR pair -> no VGPR replication, no spill)
__device__ __forceinline__ void pk_fma_bcast(f2& acc, const f2& t, uint64_t wpair) {
    asm("v_pk_fma_f32 %0, %1, %2, %0 op_sel:[0,0,0] op_sel_hi:[0,1,1]"
        : "+v"(acc) : "v"(t), "s"(wpair));
}
__device__ __forceinline__ f2 pk_mul_bcast(const f2& t, uint64_t wpair) {
    f2 d;
    asm("v_pk_mul_f32 %0, %1, %2 op_sel:[0,0] op_sel_hi:[0,1]"
        : "=v"(d) : "v"(t), "s"(wpair));
    return d;
}
// guaranteed 3-input max/min
__device__ __forceinline__ float max3f(float a, float b, float c) {
    float d; asm("v_max3_f32 %0, %1, %2, %3" : "=v"(d) : "v"(a), "v"(b), "v"(c)); return d;
}
__device__ __forceinline__ float min3f(float a, float b, float c) {
    float d; asm("v_min3_f32 %0, %1, %2, %3" : "=v"(d) : "v"(a), "v"(b), "v"(c)); return d;
}

// Load the 9 taps for output position pos into t (prefetch unit).
template <int D>
__device__ __forceinline__ void load_taps(const float* __restrict__ sel,
                                          int pos, f2 (&t)[KERNSZ]) {
    if constexpr (D == 128) {
        // halo is only 256; clamp OOB taps into the zeroed pads -> tap=0,
        // identical contribution to what 512-wide zero padding gave.
        #pragma unroll
        for (int j = 0; j < KERNSZ; ++j) {
            int off = pos + (j - 4) * D;
            if (j < 4) off = (off < -PAD) ? -PAD : off;
            if (j > 4) off = (off > MAIN + PAD - 1) ? (MAIN + PAD - 1) : off;
            t[j].x = sel[off];
        }
    } else {
        const float* p = sel + pos - 4 * D;   // pads make all 9 taps valid
        #pragma unroll
        for (int j = 0; j < KERNSZ; ++j)
            t[j].x = p[j * D];
    }
}

// Compute + accumulate for one 64-position slab whose taps are already in t.
__device__ __forceinline__ void conv_body(
    const f2 (&t)[KERNSZ], const uint64_t (&wp)[4][KERNSZ],
    bool kill63, int lane, float (&accM)[KK], uint32_t (&cnt)[KK])
{
    f2 v2[4];                              // (v0,v1)(v2,v3)(v4,v5)(v6,v7)
    #pragma unroll
    for (int c = 0; c < 4; ++c)
        v2[c] = pk_mul_bcast(t[0], wp[c][0]);
    #pragma unroll
    for (int j = 1; j < KERNSZ; ++j)
        #pragma unroll
        for (int c = 0; c < 4; ++c)
            pk_fma_bcast(v2[c], t[j], wp[c][j]);

    float v[KK] = { v2[0].x, v2[0].y, v2[1].x, v2[1].y,
                    v2[2].x, v2[2].y, v2[3].x, v2[3].y };

    float ma = max3f(v[0], v[1], v[2]);
    float mb = max3f(v[3], v[4], v[5]);
    float mc = max3f(v[6], v[7], ma);
    float mv = fmaxf(mb, mc);
    float na = min3f(v[0], v[1], v[2]);
    float nb = min3f(v[3], v[4], v[5]);
    float nc = min3f(v[6], v[7], na);
    float nv = fminf(nb, nc);

    // only invalid output position: pos==2047 on diff branch.
    // NaN never compares equal -> contributes nothing below.
    if (kill63 && lane == 63) {
        const float NANF = __uint_as_float(0x7fc00000u);
        mv = NANF; nv = NANF;
    }

    #pragma unroll
    for (int k = 0; k < KK; ++k) {
        accM[k] += (v[k] == mv) ? v[k] : 0.0f;   // exact: mv bit-equals winner
        // argmin count via ballot: v_cmp (VALU) + bcnt/add on the idle SALU
        // pipe; cnt[] is wave-uniform -> SGPRs, no tail butterfly needed
        cnt[k] += (uint32_t)__popcll(__ballot(v[k] == nv));
    }
}

// Phase 2: software-pipelined over q (prefetch taps for q+1 while computing q).
template <int D>
__device__ __forceinline__ void run_phase2(
    const float* __restrict__ sel, int lane, int dif,
    const uint64_t (&wp)[4][KERNSZ], float (&accM)[KK], uint32_t (&cnt)[KK])
{
    f2 tA[KERNSZ], tB[KERNSZ];
    load_taps<D>(sel, lane, tA);                       // q = 0
    for (int q = 0; q < 32; q += 2) {
        load_taps<D>(sel, (q + 1) * 64 + lane, tB);    // prefetch q+1
        conv_body(tA, wp, false, lane, accM, cnt);     // even q: never killed
        if (q + 2 < 32)
            load_taps<D>(sel, (q + 2) * 64 + lane, tA);// prefetch q+2
        conv_body(tB, wp, dif && (q == 30), lane, accM, cnt);
    }
}

__global__ __launch_bounds__(64, 4) void hydra_kernel(
    const float* __restrict__ X,    // [B, C, L]
    const float* __restrict__ W,    // [NDIL, 2, KK*GG, 1, KERNSZ]
    const int*   __restrict__ I,    // [NDIL, 2, GG, NPER]
    float*       __restrict__ out)  // [B, 8192]
{
    __shared__ float buf[BUFSZ];    // one wave per block; no barriers needed

    const int lane = threadIdx.x;
    const int wid  = blockIdx.x;    // 0..32767
    // task decode: wid = b*512 + di*64 + dif*32 + g
    const int b   = wid >> 9;
    const int r   = wid & 511;
    const int di  = r >> 6;
    const int r2  = r & 63;
    const int dif = r2 >> 5;
    const int g   = r2 & 31;

    float* sel = buf + PAD;

    // ---- zero halo pads (vectorized: 64 lanes x float4 = 256 floats) ----
    {
        f4 z = {0.0f, 0.0f, 0.0f, 0.0f};
        ((f4*)buf)[lane]                = z;   // left pad
        ((f4*)(buf + PAD + MAIN))[lane] = z;   // right pad
    }

    // ---- phase 1: channel-subset sum S into sel[0..2047] (dwordx4 loads) ----
    const int* Ig = I + ((size_t)((di * 2 + dif) * GG + g)) * NPER;
    const float* xb = X + (size_t)b * CC * LL;
    const f4* c0 = (const f4*)(xb + Ig[0] * LL);
    const f4* c1 = (const f4*)(xb + Ig[1] * LL);
    const f4* c2 = (const f4*)(xb + Ig[2] * LL);
    const f4* c3 = (const f4*)(xb + Ig[3] * LL);
    const f4* c4 = (const f4*)(xb + Ig[4] * LL);
    const f4* c5 = (const f4*)(xb + Ig[5] * LL);
    f4* sel4 = (f4*)sel;

    #pragma unroll 2
    for (int q = 0; q < 8; ++q) {
        int idx = q * 64 + lane;                  // float4 index, 512 quads total
        f4 s = (c0[idx] + c1[idx]) + (c2[idx] + c3[idx]) + (c4[idx] + c5[idx]);
        sel4[idx] = s;
    }

    if (dif) {
        // in-place wave-synchronous forward diff, vectorized. Per-wave LDS ops
        // are in program order: all lanes' reads of iteration q issue before
        // its writes; the extra scalar read at idx*4+4 targets data written
        // only later (lane l+1 this iter, or region of iter q+1).
        #pragma unroll 2
        for (int q = 0; q < 8; ++q) {
            int idx = q * 64 + lane;              // quad index
            f4 a  = sel4[idx];
            float an = sel[idx * 4 + 4];          // sel[2048] is the zeroed pad
            f4 v;
            v.x = a.y - a.x;
            v.y = a.z - a.y;
            v.z = a.w - a.z;
            v.w = (idx == 511) ? 0.0f : (an - a.w);   // pos 2047 -> 0
            sel4[idx] = v;
        }
    }

    // ---- weights: wave-uniform scalar loads, packed into SGPR pairs ----
    const float* Wg = W + (size_t)((di * 2 + dif) * (KK * GG) + g * KK) * KERNSZ;
    uint64_t wp[4][KERNSZ];   // wp[c][j] = (w[2c][j], w[2c+1][j])
    #pragma unroll
    for (int c = 0; c < 4; ++c)
        #pragma unroll
        for (int j = 0; j < KERNSZ; ++j) {
            uint32_t lo = __float_as_uint(Wg[(2 * c)     * KERNSZ + j]);
            uint32_t hi = __float_as_uint(Wg[(2 * c + 1) * KERNSZ + j]);
            wp[c][j] = (uint64_t)lo | ((uint64_t)hi << 32);
        }

    float    accM[KK];
    uint32_t cnt[KK];
    #pragma unroll
    for (int k = 0; k < KK; ++k) { accM[k] = 0.0f; cnt[k] = 0u; }

    switch (di) {   // block-uniform branch
        case 0: run_phase2<1>  (sel, lane, dif, wp, accM, cnt); break;
        case 1: run_phase2<2>  (sel, lane, dif, wp, accM, cnt); break;
        case 2: run_phase2<4>  (sel, lane, dif, wp, accM, cnt); break;
        case 3: run_phase2<8>  (sel, lane, dif, wp, accM, cnt); break;
        case 4: run_phase2<16> (sel, lane, dif, wp, accM, cnt); break;
        case 5: run_phase2<32> (sel, lane, dif, wp, accM, cnt); break;
        case 6: run_phase2<64> (sel, lane, dif, wp, accM, cnt); break;
        default: run_phase2<128>(sel, lane, dif, wp, accM, cnt); break;
    }

    // ---- tail: butterfly-reduce accM only; cnt is already wave-uniform ----
    float* o = out + (size_t)b * 8192 + (size_t)((di * 2 + dif) * 2) * 256 + g * KK;
    #pragma unroll
    for (int k = 0; k < KK; ++k) {
        float a = accM[k];
        #pragma unroll
        for (int off = 32; off > 0; off >>= 1)
            a += __shfl_xor(a, off, 64);
        if (lane == 0) {
            o[k]       = a;               // count_max block (which=0)
            o[256 + k] = (float)cnt[k];   // count_min block (which=1)
        }
    }
}

extern "C" void kernel_launch(void* const* d_in, const int* in_sizes, int n_in,
                              void* d_out, int out_size, void* d_ws, size_t ws_size,
                              hipStream_t stream) {
    const float* X = (const float*)d_in[0];
    const float* W = (const float*)d_in[1];
    const int*   I = (const int*)d_in[2];
    float* out = (float*)d_out;

    const int total_waves = BB * NDIL * 2 * GG;       // 32768
    hydra_kernel<<<total_waves, 64, 0, stream>>>(X, W, I, out);
}

// Round 5
// 235.811 us; speedup vs baseline: 1.5664x; 1.0326x over previous
//
#include <hip/hip_runtime.h>
#include <stdint.h>

#define BB     64
#define CC     12
#define LL     2048
#define KERNSZ 9
#define KK     8     // kernels per group
#define GG     32    // groups per branch (_G)
#define NPER   6
#define NDIL   8
#define PAD    256   // halo covers D<=64 exactly; D=128 uses clamped taps
#define MAIN   2048
#define BUFSZ  (PAD + MAIN + PAD)   // 2560 floats = 10240 B per block (1 wave)

typedef float f2 __attribute__((ext_vector_type(2)));
typedef float f4 __attribute__((ext_vector_type(4)));

// acc.{lo,hi} += t.lo * w.{lo,hi}   (tap broadcast via op_sel_hi[0]=0;
// weights are a wave-uniform SGPR pair -> no VGPR replication, no spill)
__device__ __forceinline__ void pk_fma_bcast(f2& acc, const f2& t, uint64_t wpair) {
    asm("v_pk_fma_f32 %0, %1, %2, %0 op_sel:[0,0,0] op_sel_hi:[0,1,1]"
        : "+v"(acc) : "v"(t), "s"(wpair));
}
__device__ __forceinline__ f2 pk_mul_bcast(const f2& t, uint64_t wpair) {
    f2 d;
    asm("v_pk_mul_f32 %0, %1, %2 op_sel:[0,0] op_sel_hi:[0,1]"
        : "=v"(d) : "v"(t), "s"(wpair));
    return d;
}
// guaranteed 3-input max/min
__device__ __forceinline__ float max3f(float a, float b, float c) {
    float d; asm("v_max3_f32 %0, %1, %2, %3" : "=v"(d) : "v"(a), "v"(b), "v"(c)); return d;
}
__device__ __forceinline__ float min3f(float a, float b, float c) {
    float d; asm("v_min3_f32 %0, %1, %2, %3" : "=v"(d) : "v"(a), "v"(b), "v"(c)); return d;
}

// Load the 9 taps for output position pos into t.
template <int D>
__device__ __forceinline__ void load_taps(const float* __restrict__ sel,
                                          int pos, f2 (&t)[KERNSZ]) {
    if constexpr (D == 128) {
        // halo is only 256; clamp OOB taps into the zeroed pads -> tap=0,
        // identical contribution to what 512-wide zero padding gave.
        #pragma unroll
        for (int j = 0; j < KERNSZ; ++j) {
            int off = pos + (j - 4) * D;
            if (j < 4) off = (off < -PAD) ? -PAD : off;
            if (j > 4) off = (off > MAIN + PAD - 1) ? (MAIN + PAD - 1) : off;
            t[j].x = sel[off];
        }
    } else {
        const float* p = sel + pos - 4 * D;   // pads make all 9 taps valid
        #pragma unroll
        for (int j = 0; j < KERNSZ; ++j)
            t[j].x = p[j * D];
    }
}

// Compute + accumulate for one 64-position slab whose taps are already in t.
__device__ __forceinline__ void conv_body(
    const f2 (&t)[KERNSZ], const uint64_t (&wp)[4][KERNSZ],
    bool kill63, int lane, float (&accM)[KK], uint32_t (&cnt)[KK])
{
    f2 v2[4];                              // (v0,v1)(v2,v3)(v4,v5)(v6,v7)
    #pragma unroll
    for (int c = 0; c < 4; ++c)
        v2[c] = pk_mul_bcast(t[0], wp[c][0]);
    #pragma unroll
    for (int j = 1; j < KERNSZ; ++j)
        #pragma unroll
        for (int c = 0; c < 4; ++c)
            pk_fma_bcast(v2[c], t[j], wp[c][j]);

    float v[KK] = { v2[0].x, v2[0].y, v2[1].x, v2[1].y,
                    v2[2].x, v2[2].y, v2[3].x, v2[3].y };

    float ma = max3f(v[0], v[1], v[2]);
    float mb = max3f(v[3], v[4], v[5]);
    float mc = max3f(v[6], v[7], ma);
    float mv = fmaxf(mb, mc);
    float na = min3f(v[0], v[1], v[2]);
    float nb = min3f(v[3], v[4], v[5]);
    float nc = min3f(v[6], v[7], na);
    float nv = fminf(nb, nc);

    // only invalid output position: pos==2047 on diff branch.
    // NaN never compares equal -> contributes nothing below.
    if (kill63 && lane == 63) {
        const float NANF = __uint_as_float(0x7fc00000u);
        mv = NANF; nv = NANF;
    }

    // argmin count via ballot: v_cmp (VALU) + bcnt/add on the idle SALU pipe;
    // cnt[] is wave-uniform -> SGPRs, no tail butterfly needed
    #pragma unroll
    for (int k = 0; k < KK; ++k)
        cnt[k] += (uint32_t)__popcll(__ballot(v[k] == nv));

    // count_max accumulate via v_cmpx + predicated add: 2 VALU per k instead of
    // cmp+cndmask+add (3). Winning lanes (v[k]==mv, i.e. v[k] bit-equals mv)
    // add mv under the exec mask; losers/NaN-killed lanes keep accM unchanged.
    // exec is saved/restored inside the block; vcc clobbered.
    uint64_t es;
    asm volatile(
        "s_mov_b64 %[es], exec\n\t"
        "v_cmpx_eq_f32 vcc, %[x0], %[mv]\n\t"
        "v_add_f32 %[a0], %[a0], %[mv]\n\t"
        "s_mov_b64 exec, %[es]\n\t"
        "v_cmpx_eq_f32 vcc, %[x1], %[mv]\n\t"
        "v_add_f32 %[a1], %[a1], %[mv]\n\t"
        "s_mov_b64 exec, %[es]\n\t"
        "v_cmpx_eq_f32 vcc, %[x2], %[mv]\n\t"
        "v_add_f32 %[a2], %[a2], %[mv]\n\t"
        "s_mov_b64 exec, %[es]\n\t"
        "v_cmpx_eq_f32 vcc, %[x3], %[mv]\n\t"
        "v_add_f32 %[a3], %[a3], %[mv]\n\t"
        "s_mov_b64 exec, %[es]\n\t"
        "v_cmpx_eq_f32 vcc, %[x4], %[mv]\n\t"
        "v_add_f32 %[a4], %[a4], %[mv]\n\t"
        "s_mov_b64 exec, %[es]\n\t"
        "v_cmpx_eq_f32 vcc, %[x5], %[mv]\n\t"
        "v_add_f32 %[a5], %[a5], %[mv]\n\t"
        "s_mov_b64 exec, %[es]\n\t"
        "v_cmpx_eq_f32 vcc, %[x6], %[mv]\n\t"
        "v_add_f32 %[a6], %[a6], %[mv]\n\t"
        "s_mov_b64 exec, %[es]\n\t"
        "v_cmpx_eq_f32 vcc, %[x7], %[mv]\n\t"
        "v_add_f32 %[a7], %[a7], %[mv]\n\t"
        "s_mov_b64 exec, %[es]"
        : [es]"=&s"(es),
          [a0]"+v"(accM[0]), [a1]"+v"(accM[1]),
          [a2]"+v"(accM[2]), [a3]"+v"(accM[3]),
          [a4]"+v"(accM[4]), [a5]"+v"(accM[5]),
          [a6]"+v"(accM[6]), [a7]"+v"(accM[7])
        : [x0]"v"(v[0]), [x1]"v"(v[1]), [x2]"v"(v[2]), [x3]"v"(v[3]),
          [x4]"v"(v[4]), [x5]"v"(v[5]), [x6]"v"(v[6]), [x7]"v"(v[7]),
          [mv]"v"(mv)
        : "vcc");
}

// Phase 2: simple loop (prefetch pipeline measured null in R4); unroll 4 so
// tap addresses fold into immediate ds_read offsets.
template <int D>
__device__ __forceinline__ void run_phase2(
    const float* __restrict__ sel, int lane, int dif,
    const uint64_t (&wp)[4][KERNSZ], float (&accM)[KK], uint32_t (&cnt)[KK])
{
    #pragma unroll 4
    for (int q = 0; q < 32; ++q) {
        f2 t[KERNSZ];
        load_taps<D>(sel, q * 64 + lane, t);
        conv_body(t, wp, dif && (q == 31), lane, accM, cnt);
    }
}

__global__ __launch_bounds__(64, 4) void hydra_kernel(
    const float* __restrict__ X,    // [B, C, L]
    const float* __restrict__ W,    // [NDIL, 2, KK*GG, 1, KERNSZ]
    const int*   __restrict__ I,    // [NDIL, 2, GG, NPER]
    float*       __restrict__ out)  // [B, 8192]
{
    __shared__ float buf[BUFSZ];    // one wave per block; no barriers needed

    const int lane = threadIdx.x;
    const int wid  = blockIdx.x;    // 0..32767
    // task decode: wid = b*512 + di*64 + dif*32 + g
    const int b   = wid >> 9;
    const int r   = wid & 511;
    const int di  = r >> 6;
    const int r2  = r & 63;
    const int dif = r2 >> 5;
    const int g   = r2 & 31;

    float* sel = buf + PAD;

    // ---- zero halo pads (vectorized: 64 lanes x float4 = 256 floats) ----
    {
        f4 z = {0.0f, 0.0f, 0.0f, 0.0f};
        ((f4*)buf)[lane]                = z;   // left pad
        ((f4*)(buf + PAD + MAIN))[lane] = z;   // right pad
    }

    // ---- phase 1: channel-subset sum S into sel[0..2047] (dwordx4 loads) ----
    const int* Ig = I + ((size_t)((di * 2 + dif) * GG + g)) * NPER;
    const float* xb = X + (size_t)b * CC * LL;
    const f4* c0 = (const f4*)(xb + Ig[0] * LL);
    const f4* c1 = (const f4*)(xb + Ig[1] * LL);
    const f4* c2 = (const f4*)(xb + Ig[2] * LL);
    const f4* c3 = (const f4*)(xb + Ig[3] * LL);
    const f4* c4 = (const f4*)(xb + Ig[4] * LL);
    const f4* c5 = (const f4*)(xb + Ig[5] * LL);
    f4* sel4 = (f4*)sel;

    #pragma unroll 2
    for (int q = 0; q < 8; ++q) {
        int idx = q * 64 + lane;                  // float4 index, 512 quads total
        f4 s = (c0[idx] + c1[idx]) + (c2[idx] + c3[idx]) + (c4[idx] + c5[idx]);
        sel4[idx] = s;
    }

    if (dif) {
        // in-place wave-synchronous forward diff, vectorized. Per-wave LDS ops
        // are in program order: all lanes' reads of iteration q issue before
        // its writes; the extra scalar read at idx*4+4 targets data written
        // only later (lane l+1 this iter, or region of iter q+1).
        #pragma unroll 2
        for (int q = 0; q < 8; ++q) {
            int idx = q * 64 + lane;              // quad index
            f4 a  = sel4[idx];
            float an = sel[idx * 4 + 4];          // sel[2048] is the zeroed pad
            f4 v;
            v.x = a.y - a.x;
            v.y = a.z - a.y;
            v.z = a.w - a.z;
            v.w = (idx == 511) ? 0.0f : (an - a.w);   // pos 2047 -> 0
            sel4[idx] = v;
        }
    }

    // ---- weights: wave-uniform scalar loads, packed into SGPR pairs ----
    const float* Wg = W + (size_t)((di * 2 + dif) * (KK * GG) + g * KK) * KERNSZ;
    uint64_t wp[4][KERNSZ];   // wp[c][j] = (w[2c][j], w[2c+1][j])
    #pragma unroll
    for (int c = 0; c < 4; ++c)
        #pragma unroll
        for (int j = 0; j < KERNSZ; ++j) {
            uint32_t lo = __float_as_uint(Wg[(2 * c)     * KERNSZ + j]);
            uint32_t hi = __float_as_uint(Wg[(2 * c + 1) * KERNSZ + j]);
            wp[c][j] = (uint64_t)lo | ((uint64_t)hi << 32);
        }

    float    accM[KK];
    uint32_t cnt[KK];
    #pragma unroll
    for (int k = 0; k < KK; ++k) { accM[k] = 0.0f; cnt[k] = 0u; }

    switch (di) {   // block-uniform branch
        case 0: run_phase2<1>  (sel, lane, dif, wp, accM, cnt); break;
        case 1: run_phase2<2>  (sel, lane, dif, wp, accM, cnt); break;
        case 2: run_phase2<4>  (sel, lane, dif, wp, accM, cnt); break;
        case 3: run_phase2<8>  (sel, lane, dif, wp, accM, cnt); break;
        case 4: run_phase2<16> (sel, lane, dif, wp, accM, cnt); break;
        case 5: run_phase2<32> (sel, lane, dif, wp, accM, cnt); break;
        case 6: run_phase2<64> (sel, lane, dif, wp, accM, cnt); break;
        default: run_phase2<128>(sel, lane, dif, wp, accM, cnt); break;
    }

    // ---- tail: butterfly-reduce accM only; cnt is already wave-uniform ----
    float* o = out + (size_t)b * 8192 + (size_t)((di * 2 + dif) * 2) * 256 + g * KK;
    #pragma unroll
    for (int k = 0; k < KK; ++k) {
        float a = accM[k];
        #pragma unroll
        for (int off = 32; off > 0; off >>= 1)
            a += __shfl_xor(a, off, 64);
        if (lane == 0) {
            o[k]       = a;               // count_max block (which=0)
            o[256 + k] = (float)cnt[k];   // count_min block (which=1)
        }
    }
}

extern "C" void kernel_launch(void* const* d_in, const int* in_sizes, int n_in,
                              void* d_out, int out_size, void* d_ws, size_t ws_size,
                              hipStream_t stream) {
    const float* X = (const float*)d_in[0];
    const float* W = (const float*)d_in[1];
    const int*   I = (const int*)d_in[2];
    float* out = (float*)d_out;

    const int total_waves = BB * NDIL * 2 * GG;       // 32768
    hydra_kernel<<<total_waves, 64, 0, stream>>>(X, W, I, out);
}